// Round 8
// baseline (5356.332 us; speedup 1.0000x reference)
//
#include <hip/hip_runtime.h>

// ============================================================================
// 2-layer LSTM (B=64,T=512,D=256,H=1024) + linear, fp32.
// Persistent kernel, int16 weights/acts split into two int8 planes,
// 3x i8-MFMA per K=32, fragment-native h layout (R10), lag-2 diagonal (R11),
// one-hop subset polling (R12, proven 4.30ms).
// R13 (REVERTED): cached h + L2 inv: 5.86ms.
// R14/R15 (REVERTED): counted-poll sync edits -> wrong results. BANNED.
// R16 (REVERTED): batch rotation: 4.53ms (lockstep same-line reads GOOD).
// R17/R18 (REVERTED): new pbuf cross-WG channel -> NaN. Cross-WG protocol
//   frozen at R12 byte-for-byte.
// R19 (NEUTRAL, kept machinery): intra-WG K-split, 4 waves, int-exact LDS
//   exchange -- proved the exchange correct; showed stream DEPTH is not the
//   binder (drain RT count is).
// R20: L1 STREAM-PARALLELISM. L1's serial phase was pre-guard + h0 stream +
//   main poll + h2 stream (~8.4us == measured cadence). The two streams have
//   independent guards (h0: L0>=p-1; h2: L1>=p), so split by WAVE:
//     waves str=0 (w=0,1; RB=w&1): per-wave pre-guard poll -> h0(p-2) full
//       stream (ksteps 0..31) -> combiner.
//     waves str=1 (w=2,3; RB=w&1): per-wave main poll (L1>=p) -> h2(p-3)
//       full stream (ksteps 32..63) -> publish int32 acc via LDS (R19).
//   Per-wave polls guard only that wave's own reads (same drained-acquire
//   primitive + thresholds as R12); all cross-wave effects (gbuf, h2 store,
//   slot post) are after the retained exchange/arrival barriers, preserving
//   every R12 happens-before edge transitively. L0: R19-verbatim.
//   Cross-WG slots/rings/thresholds/arrival: R12-verbatim.
// ============================================================================

#define T_STEPS 512
#define NWG 256
#define LDS_W     131072                  // [64 ksteps][2 planes][64 lanes][16B]
#define LDS_GBUF  (64 * 33 * 4)           // 8448, padded stride 33
#define LDS_CBUF  (64 * 9 * 4)            // 2304, padded stride 9
#define LDS_OFFS  (32 * 4)
#define LDS_PEX   16384                   // [2 rb][32 vals][64 lanes] int
#define SMEM_BYTES (LDS_W + LDS_GBUF + LDS_CBUF + LDS_OFFS + LDS_PEX) // 158336

typedef int v4i  __attribute__((ext_vector_type(4)));
typedef int v16i __attribute__((ext_vector_type(16)));

__device__ __forceinline__ v16i zero16() {
    v16i z;
#pragma unroll
    for (int i = 0; i < 16; ++i) z[i] = 0;
    return z;
}

// One 8-kstep batch from fragment layout: 16 lane-contiguous dwordx4
// (sc0 sc1, MALL-direct), NO trailing wait. kstep s at +s*2048, A0/A1 +0/+16.
__device__ __forceinline__ void load_f16_nw(const char* b0p, v4i* o) {
    const char* b1p = b0p + 4096;
    const char* b2p = b0p + 8192;
    const char* b3p = b0p + 12288;
    asm volatile(
        "global_load_dwordx4 %0, %16, off sc0 sc1\n\t"
        "global_load_dwordx4 %1, %16, off offset:16 sc0 sc1\n\t"
        "global_load_dwordx4 %2, %16, off offset:2048 sc0 sc1\n\t"
        "global_load_dwordx4 %3, %16, off offset:2064 sc0 sc1\n\t"
        "global_load_dwordx4 %4, %17, off sc0 sc1\n\t"
        "global_load_dwordx4 %5, %17, off offset:16 sc0 sc1\n\t"
        "global_load_dwordx4 %6, %17, off offset:2048 sc0 sc1\n\t"
        "global_load_dwordx4 %7, %17, off offset:2064 sc0 sc1\n\t"
        "global_load_dwordx4 %8, %18, off sc0 sc1\n\t"
        "global_load_dwordx4 %9, %18, off offset:16 sc0 sc1\n\t"
        "global_load_dwordx4 %10, %18, off offset:2048 sc0 sc1\n\t"
        "global_load_dwordx4 %11, %18, off offset:2064 sc0 sc1\n\t"
        "global_load_dwordx4 %12, %19, off sc0 sc1\n\t"
        "global_load_dwordx4 %13, %19, off offset:16 sc0 sc1\n\t"
        "global_load_dwordx4 %14, %19, off offset:2048 sc0 sc1\n\t"
        "global_load_dwordx4 %15, %19, off offset:2064 sc0 sc1"
        : "=&v"(o[0]), "=&v"(o[1]), "=&v"(o[2]), "=&v"(o[3]),
          "=&v"(o[4]), "=&v"(o[5]), "=&v"(o[6]), "=&v"(o[7]),
          "=&v"(o[8]), "=&v"(o[9]), "=&v"(o[10]), "=&v"(o[11]),
          "=&v"(o[12]), "=&v"(o[13]), "=&v"(o[14]), "=&v"(o[15])
        : "v"(b0p), "v"(b1p), "v"(b2p), "v"(b3p)
        : "memory");
}

#define WAIT_BIND(cntstr, b)                                                   \
    asm volatile("s_waitcnt vmcnt(" cntstr ")"                                 \
        : "+v"((b)[0]), "+v"((b)[1]), "+v"((b)[2]), "+v"((b)[3]),              \
          "+v"((b)[4]), "+v"((b)[5]), "+v"((b)[6]), "+v"((b)[7]),              \
          "+v"((b)[8]), "+v"((b)[9]), "+v"((b)[10]), "+v"((b)[11]),            \
          "+v"((b)[12]), "+v"((b)[13]), "+v"((b)[14]), "+v"((b)[15])           \
        :: "memory")

__device__ __forceinline__ void st16_wt(void* p, v4i v) {      // write-through MALL
    asm volatile("global_store_dwordx4 %0, %1, off sc0 sc1" :: "v"(p), "v"(v) : "memory");
}
__device__ __forceinline__ void store_slot(unsigned* p, unsigned v) {
    asm volatile("global_store_dword %0, %1, off sc0 sc1" :: "v"(p), "v"(v) : "memory");
}
__device__ __forceinline__ v4i ld4_mall(const unsigned* p) {
    v4i r;
    asm volatile("global_load_dwordx4 %0, %1, off sc0 sc1\n\ts_waitcnt vmcnt(0)"
                 : "=v"(r) : "v"(p) : "memory");
    return r;
}
__device__ __forceinline__ void waitcnt0() {
    asm volatile("s_waitcnt vmcnt(0)" ::: "memory");
}
__device__ __forceinline__ bool slots_ok(v4i v, unsigned thr) {
    return ((unsigned)v.x >= thr) & ((unsigned)v.y >= thr) &
           ((unsigned)v.z >= thr) & ((unsigned)v.w >= thr);
}

__device__ __forceinline__ void split_a(v4i A0, v4i A1, v4i& HI, v4i& LO) {
    HI.x = (int)__builtin_amdgcn_perm((unsigned)A0.y, (unsigned)A0.x, 0x07050301u);
    HI.y = (int)__builtin_amdgcn_perm((unsigned)A0.w, (unsigned)A0.z, 0x07050301u);
    HI.z = (int)__builtin_amdgcn_perm((unsigned)A1.y, (unsigned)A1.x, 0x07050301u);
    HI.w = (int)__builtin_amdgcn_perm((unsigned)A1.w, (unsigned)A1.z, 0x07050301u);
    LO.x = (int)(__builtin_amdgcn_perm((unsigned)A0.y, (unsigned)A0.x, 0x06040200u) ^ 0x80808080u);
    LO.y = (int)(__builtin_amdgcn_perm((unsigned)A0.w, (unsigned)A0.z, 0x06040200u) ^ 0x80808080u);
    LO.z = (int)(__builtin_amdgcn_perm((unsigned)A1.y, (unsigned)A1.x, 0x06040200u) ^ 0x80808080u);
    LO.w = (int)(__builtin_amdgcn_perm((unsigned)A1.w, (unsigned)A1.z, 0x06040200u) ^ 0x80808080u);
}

__device__ __forceinline__ void consume8(const v4i* hb, const char* wbase,
                                         v16i& ahh, v16i& amid)
{
#pragma unroll
    for (int s = 0; s < 8; ++s) {
        v4i HI, LO; split_a(hb[2 * s], hb[2 * s + 1], HI, LO);
        v4i BH = *(const v4i*)(wbase + s * 2048);
        v4i BL = *(const v4i*)(wbase + s * 2048 + 1024);
        ahh  = __builtin_amdgcn_mfma_i32_32x32x32_i8(HI, BH, ahh, 0, 0, 0);
        amid = __builtin_amdgcn_mfma_i32_32x32x32_i8(HI, BL, amid, 0, 0, 0);
        amid = __builtin_amdgcn_mfma_i32_32x32x32_i8(LO, BH, amid, 0, 0, 0);
    }
}

// plain cached-load kstep (x segment only; xq stays row-major)
__device__ __forceinline__ void kstep(const short* __restrict__ ap,
                                      const char* __restrict__ wl,
                                      v16i& ahh, v16i& amid)
{
    v4i A0 = *(const v4i*)ap;
    v4i A1 = *(const v4i*)(ap + 8);
    v4i HI, LO; split_a(A0, A1, HI, LO);
    v4i BH = *(const v4i*)wl;
    v4i BL = *(const v4i*)(wl + 1024);
    ahh  = __builtin_amdgcn_mfma_i32_32x32x32_i8(HI, BH, ahh, 0, 0, 0);
    amid = __builtin_amdgcn_mfma_i32_32x32x32_i8(HI, BL, amid, 0, 0, 0);
    amid = __builtin_amdgcn_mfma_i32_32x32x32_i8(LO, BH, amid, 0, 0, 0);
}

// ---------------------------------------------------------------------------
__global__ void quant_x(const float* __restrict__ x, short* __restrict__ xq, int n)
{
    int i = blockIdx.x * 256 + threadIdx.x;
    if (i < n) {
        float v = x[i] * 2048.f;
        v = fminf(fmaxf(v, -32767.f), 32767.f);
        xq[i] = (short)__float2int_rn(v);
    }
}

// prep: quantize + gate-reorder + fragment-tile weights into per-WG LDS images.
__global__ void quant_w(const float* __restrict__ wih0, const float* __restrict__ whh0,
                        const float* __restrict__ wih1, const float* __restrict__ whh1,
                        char* __restrict__ wimg)
{
    int gid = blockIdx.x * 256 + threadIdx.x;       // 256*64*64 = 1048576 threads
    if (gid >= 256 * 64 * 64) return;
    int lane = gid & 63;
    int s    = (gid >> 6) & 63;
    int wg   = gid >> 12;
    int layer = wg >> 7, nblk = wg & 127;
    int col = nblk * 32 + (lane & 31);
    int ro  = (col & 3) * 1024 + (col >> 2);        // original gate-blocked row
    int k0  = s * 32 + (lane >> 5) * 16;
    char* dst = wimg + (size_t)wg * LDS_W + s * 2048 + lane * 16;
#pragma unroll
    for (int j = 0; j < 16; ++j) {
        int k = k0 + j;
        float w = 0.f;
        if (layer == 0) {
            if (k < 256)       w = wih0[ro * 256 + k];
            else if (k < 1280) w = whh0[ro * 1024 + (k - 256)];
        } else {
            if (k < 1024)      w = wih1[ro * 1024 + k];
            else               w = whh1[ro * 1024 + (k - 1024)];
        }
        int q  = __float2int_rn(w * 524288.f);      // 2^19, |q|<=16384
        int hi = (q + 128) >> 8;
        int lo = q - (hi << 8);
        dst[j]        = (char)hi;
        dst[1024 + j] = (char)lo;
    }
}

// ---------------------------------------------------------------------------
__global__ void __launch_bounds__(256, 1) lstm_main(
    const short* __restrict__ xq, const char* __restrict__ wimg,
    const float* __restrict__ bih0, const float* __restrict__ bhh0,
    const float* __restrict__ bih1, const float* __restrict__ bhh1,
    short* __restrict__ h0q, short* __restrict__ h2q,
    float* __restrict__ h2f, unsigned* gslots)
{
    extern __shared__ char smem[];
    char*  wlds = smem;
    float* gbuf = (float*)(smem + LDS_W);                       // [64][33]
    float* cbuf = (float*)(smem + LDS_W + LDS_GBUF);            // [64][9]
    float* offs = (float*)(smem + LDS_W + LDS_GBUF + LDS_CBUF); // [32]
    int*   pexch = (int*)(smem + LDS_W + LDS_GBUF + LDS_CBUF + LDS_OFFS);

    const int wg    = blockIdx.x;
    const int layer = wg >> 7;
    const int nblk  = wg & 127;
    const int tid   = threadIdx.x;
    const int lane  = tid & 63;
    const int w     = tid >> 6;                   // wave 0..3
    // L0 mapping (R19): RB=w>>1 (rowblock), kh=w&1 (K-half of h0 stream)
    const int RB    = w >> 1;
    const int kh    = w & 1;
    // L1 mapping (R20): rb1=w&1 (rowblock), str=w>>1 (0: h0 stream, 1: h2)
    const int rb1   = w & 1;
    const int str   = w >> 1;
    const float inv33 = 1.1641532182693481e-10f;  // 2^-33

    // stage this WG's weight image into LDS (128KB)
    {
        const v4i* src = (const v4i*)(wimg + (size_t)wg * LDS_W);
        v4i* dst = (v4i*)wlds;
        for (int i = tid; i < LDS_W / 16; i += 256) dst[i] = src[i];
    }
    for (int i = tid; i < 64 * 9; i += 256) cbuf[i] = 0.f;
    __syncthreads();

    // per-col constant: 128*colsum16*inv_scale (LO'=-128 bias comp) + gate bias
    if (tid < 32) {
        const int c  = tid;
        const int ns = (layer == 0) ? 40 : 64;
        int cs_x = 0, cs_h = 0;
        for (int s = 0; s < ns; ++s) {
            int sum = 0;
#pragma unroll
            for (int half = 0; half < 2; ++half) {
                const signed char* ph = (const signed char*)(wlds + s * 2048 + (half * 32 + c) * 16);
#pragma unroll
                for (int j = 0; j < 16; ++j)
                    sum += 256 * (int)ph[j] + (int)ph[1024 + j];
            }
            if (layer == 0 && s < 8) cs_x += sum; else cs_h += sum;
        }
        const int col = nblk * 32 + c;
        const int ro  = (col & 3) * 1024 + (col >> 2);
        const float bias = (layer == 0) ? (bih0[ro] + bhh0[ro]) : (bih1[ro] + bhh1[ro]);
        float off = 128.f * (float)cs_h * inv33 + bias;
        if (layer == 0) off += 128.f * (float)cs_x * 9.313225746154785e-10f; // 2^-30
        offs[c] = off;
    }
    __syncthreads();

    const int mrow = RB * 32 + (lane & 31);           // batch row (x segment, L0)
    const int ksub = (lane >> 5) * 16;                // k sub-offset (x segment)
    // producer store constants: units j0..j0+7, one 16B chunk per row
    const int j0   = nblk * 8;
    const int sj   = j0 >> 5;
    const int hbj  = (j0 >> 4) & 1;
    const int inj  = (j0 & 15) * 2;

    // phase p: L0 computes step p (p<T); L1 computes step p-2 (p>=2).
    for (int p = 0; p <= T_STEPS + 1; ++p) {
        const bool actL0 = (layer == 0) && (p < T_STEPS);
        const bool actL1 = (layer == 1) && (p >= 2);
        const bool active = actL0 || actL1;

        v16i ahh = zero16(), amid = zero16();

        if (layer == 0) {
            // ============ L0: R19-verbatim (K-split, wave0 polls) ==========
            v16i ax = zero16(), mx = zero16();
            if (actL0 && kh == 0) {
                const short* axp = xq + ((size_t)mrow * 512 + p) * 256 + ksub;
#pragma unroll
                for (int s = 0; s < 8; ++s)
                    kstep(axp + s * 32, wlds + s * 2048 + lane * 16, ax, mx);
            }
            // main poll [R12-verbatim]: wave0 lanes 0-31 L0>=p (RAW h0(p-1));
            // lanes 32-63 L1>=p-5 (WAR lag-guard, h0 ring=8).
            if (p > 0) {
                if (tid < 64) {
                    const unsigned thr = (tid < 32) ? (unsigned)p
                                                    : (unsigned)(p > 5 ? p - 5 : 0);
                    const unsigned* sp = gslots + tid * 4;
                    for (;;) {
                        v4i v = ld4_mall(sp);
                        if (!__ballot(!slots_ok(v, thr))) break;
                        __builtin_amdgcn_s_sleep(3);
                    }
                }
                __syncthreads();
                asm volatile("" ::: "memory");
            }
            // h0(p-1) half-stream (weight ksteps 8..39, kh half); skip p=0
            if (actL0 && p > 0) {
                const char* f0 = (const char*)h0q + ((p - 1) & 7) * 131072
                               + RB * 65536 + lane * 32 + kh * 32768;
                const char* W = wlds + lane * 16 + (8 + kh * 16) * 2048;
                v4i b0[16], b1[16];
                waitcnt0();
                load_f16_nw(f0, b0);
                load_f16_nw(f0 + 16384, b1);
                WAIT_BIND("16", b0); consume8(b0, W, ahh, amid);
                WAIT_BIND("0", b1);  consume8(b1, W + 8 * 2048, ahh, amid);
            }
            // merge x-projection (2^-30 = 8 * 2^-33; int-exact, no overflow)
            if (actL0 && kh == 0) {
#pragma unroll
                for (int r = 0; r < 16; ++r) {
                    ahh[r]  += 8 * ax[r];
                    amid[r] += 8 * mx[r];
                }
            }
        } else {
            // ============ L1: R20 stream-parallel across waves =============
            if (str == 0) {
                // pre-guard PER-WAVE (guards only this wave's h0 reads):
                // lanes 0-31 check L0 slots >= p-1 [R12 threshold].
                if (actL1) {
                    const unsigned thr = (lane < 32) ? (unsigned)(p - 1) : 0u;
                    const unsigned* sp = gslots + (lane & 31) * 4;
                    for (;;) {
                        v4i v = ld4_mall(sp);
                        if (!__ballot(!slots_ok(v, thr))) break;
                        __builtin_amdgcn_s_sleep(3);
                    }
                    asm volatile("" ::: "memory");
                    // h0(p-2) full stream for rb1 (weight ksteps 0..31)
                    const char* f0 = (const char*)h0q + ((p - 2) & 7) * 131072
                                   + rb1 * 65536 + lane * 32;
                    const char* W = wlds + lane * 16;
                    v4i b0[16], b1[16];
                    waitcnt0();
                    load_f16_nw(f0, b0);
                    load_f16_nw(f0 + 16384, b1);
                    WAIT_BIND("16", b0); consume8(b0, W, ahh, amid);
                    load_f16_nw(f0 + 32768, b0);
                    WAIT_BIND("16", b1); consume8(b1, W + 8 * 2048, ahh, amid);
                    load_f16_nw(f0 + 49152, b1);
                    WAIT_BIND("16", b0); consume8(b0, W + 16 * 2048, ahh, amid);
                    WAIT_BIND("0", b1);  consume8(b1, W + 24 * 2048, ahh, amid);
                }
            } else {
                // main poll PER-WAVE [R12 threshold]: L1 slots >= p
                // (RAW h2(p-3); WAR implied, h2 ring=4).
                if (p > 0) {
                    const unsigned* sp = gslots + 128 + (lane & 31) * 4;
                    const unsigned thr = (unsigned)p;
                    for (;;) {
                        v4i v = ld4_mall(sp);
                        if (!__ballot(!slots_ok(v, thr))) break;
                        __builtin_amdgcn_s_sleep(3);
                    }
                    asm volatile("" ::: "memory");
                }
                // h2(p-3) full stream for rb1 (weight ksteps 32..63); skip p<=2
                if (actL1 && p > 2) {
                    const char* f2 = (const char*)h2q + ((p - 3) & 3) * 131072
                                   + rb1 * 65536 + lane * 32;
                    const char* W = wlds + lane * 16 + 32 * 2048;
                    v4i b0[16], b1[16];
                    waitcnt0();
                    load_f16_nw(f2, b0);
                    load_f16_nw(f2 + 16384, b1);
                    WAIT_BIND("16", b0); consume8(b0, W, ahh, amid);
                    load_f16_nw(f2 + 32768, b0);
                    WAIT_BIND("16", b1); consume8(b1, W + 8 * 2048, ahh, amid);
                    load_f16_nw(f2 + 49152, b1);
                    WAIT_BIND("16", b0); consume8(b0, W + 16 * 2048, ahh, amid);
                    WAIT_BIND("0", b1);  consume8(b1, W + 24 * 2048, ahh, amid);
                }
            }
        }

        // ---- partial exchange (int-exact): publisher -> combiner ----------
        // L0: kh1 publishes (K-half), kh0 combines [R19].
        // L1: str1 publishes (h2-part; zeros at p==2), str0 combines.
        {
            const int  rbIdx = (layer == 0) ? RB : rb1;
            const bool isPub = (layer == 0) ? (kh == 1) : (str == 1);
            if (active && isPub) {
                int* pxm = pexch + rbIdx * 2048;
#pragma unroll
                for (int i = 0; i < 16; ++i) pxm[i * 64 + lane] = ahh[i];
#pragma unroll
                for (int i = 0; i < 16; ++i) pxm[(16 + i) * 64 + lane] = amid[i];
            }
            __syncthreads();
            if (active && !isPub) {
                const int* pxm = pexch + rbIdx * 2048;
                const int rbase = rbIdx * 32 + 4 * (lane >> 5);
                const int c = lane & 31;
#pragma unroll
                for (int r = 0; r < 16; ++r) {
                    int th = ahh[r]  + pxm[r * 64 + lane];
                    int tm = amid[r] + pxm[(16 + r) * 64 + lane];
                    float g = ((float)th * 65536.f + (float)tm * 256.f) * inv33
                            + offs[c];
                    int row = rbase + (r & 3) + 8 * (r >> 2);
                    gbuf[row * 33 + c] = g;
                }
            }
        }
        __syncthreads();
        if (active && tid < 64) {
            // state update [R12-verbatim]: thread = row, 8 units, ONE 16B store
            const int r = tid;
            unsigned hq[8];
            float hf[8];
#pragma unroll
            for (int u = 0; u < 8; ++u) {
                const float gi = gbuf[r * 33 + 4 * u + 0];
                const float gf = gbuf[r * 33 + 4 * u + 1];
                const float gg = gbuf[r * 33 + 4 * u + 2];
                const float go = gbuf[r * 33 + 4 * u + 3];
                const float i_ = 1.f / (1.f + __expf(-gi));
                const float f_ = 1.f / (1.f + __expf(-gf));
                const float g_ = 1.f - 2.f / (__expf(2.f * gg) + 1.f);
                const float o_ = 1.f / (1.f + __expf(-go));
                float c_ = f_ * cbuf[r * 9 + u] + i_ * g_;
                cbuf[r * 9 + u] = c_;
                const float h_ = o_ * (1.f - 2.f / (__expf(2.f * c_) + 1.f));
                hq[u] = (unsigned)(unsigned short)(short)__float2int_rn(h_ * 16384.f);
                hf[u] = h_;
            }
            v4i pk;
            pk.x = (int)(hq[0] | (hq[1] << 16));
            pk.y = (int)(hq[2] | (hq[3] << 16));
            pk.z = (int)(hq[4] | (hq[5] << 16));
            pk.w = (int)(hq[6] | (hq[7] << 16));
            // L0 writes h0(p) slot p&7; L1 writes h2(p-2) slot (p-2)&3
            char* hw = (layer == 0)
                     ? (char*)h0q + (p & 7) * 131072
                     : (char*)h2q + ((p - 2) & 3) * 131072;
            hw += (r >> 5) * 65536 + sj * 2048 + ((r & 31) + 32 * hbj) * 32 + inj;
            st16_wt(hw, pk);
            if (layer == 1 && p == T_STEPS + 1) {
#pragma unroll
                for (int u = 0; u < 8; ++u) h2f[r * 1024 + j0 + u] = hf[u];
            }
        }
        // ---- arrival [R12-verbatim] (value p+1, release) ------------------
        if (p < T_STEPS + 1) {
            waitcnt0();
            __syncthreads();
            if (tid == 0)
                store_slot(gslots + wg, (unsigned)(p + 1));
        }
    }
}

// ---------------------------------------------------------------------------
__global__ void final_lin(const float* __restrict__ h2f, const float* __restrict__ wlin,
                          const float* __restrict__ blin, float* __restrict__ out)
{
    const int b = blockIdx.x;
    const int l = threadIdx.x;
    float s = 0.f;
    for (int j = l; j < 1024; j += 64) s += h2f[b * 1024 + j] * wlin[j];
#pragma unroll
    for (int off = 32; off; off >>= 1) s += __shfl_down(s, off);
    if (l == 0) out[b] = s + blin[0];
}

// ---------------------------------------------------------------------------
extern "C" void kernel_launch(void* const* d_in, const int* in_sizes, int n_in,
                              void* d_out, int out_size, void* d_ws, size_t ws_size,
                              hipStream_t stream)
{
    const float* x    = (const float*)d_in[0];
    const float* wih0 = (const float*)d_in[1];
    const float* whh0 = (const float*)d_in[2];
    const float* bih0 = (const float*)d_in[3];
    const float* bhh0 = (const float*)d_in[4];
    const float* wih1 = (const float*)d_in[5];
    const float* whh1 = (const float*)d_in[6];
    const float* bih1 = (const float*)d_in[7];
    const float* bhh1 = (const float*)d_in[8];
    const float* wlin = (const float*)d_in[9];
    const float* blin = (const float*)d_in[10];

    // workspace layout [R12-verbatim]
    char* ws = (char*)d_ws;
    unsigned* gslots = (unsigned*)ws;                    // 256 x 4B packed (16 lines)
    short* h0q = (short*)(ws + 65536);                   // [8 slots][128KB] fragment ring
    short* h2q = (short*)(ws + 65536 + 1048576);         // [4 slots][128KB] fragment ring
    float* h2f = (float*)(ws + 65536 + 1572864);         // [64][1024] f32 = 256KB
    short* xq  = (short*)(ws + 65536 + 1835008);         // 16MB
    char*  wimg = ws + 65536 + 1835008 + 16777216;       // 256 * 128KB = 32MB

    // zero arrival slots (h rings are written before any read)
    hipMemsetAsync(ws, 0, 65536, stream);

    quant_x<<<32768, 256, 0, stream>>>(x, xq, 64 * 512 * 256);
    quant_w<<<4096, 256, 0, stream>>>(wih0, whh0, wih1, whh1, wimg);

    hipFuncSetAttribute((const void*)lstm_main,
        hipFuncAttributeMaxDynamicSharedMemorySize, SMEM_BYTES);

    lstm_main<<<NWG, 256, SMEM_BYTES, stream>>>(xq, wimg, bih0, bhh0, bih1, bhh1,
                                                h0q, h2q, h2f, gslots);
    final_lin<<<64, 64, 0, stream>>>(h2f, wlin, blin, (float*)d_out);
}